// Round 4
// baseline (451.131 us; speedup 1.0000x reference)
//
#include <hip/hip_runtime.h>
#include <hip/hip_bf16.h>

// BitLevelMapper: bits [B,16] int32 {0,1} (mem index j holds value bit 15-j),
// tables [16, 32768] float32 {0,1}. For bit i: addr = value of bits 0..i-1,
// flip = tables[i][addr], out bit i = bit i ^ flip. Output float32, reversed
// layout like input.
//
// Live table = sum_i 2^i = 65535 bits ~= 8 KB packed -> LDS.
// R1: lane-contiguous global IO (16 B/lane), wave-shuffle row assembly.
// R2/R3: 2 chunks/wave fully unrolled, all 8 loads issued up front (2x MLP);
//     nontemporal output stores via native vector type (write-once data).

#define PACK_WORDS 2048   // 65536 bits (65535 used), 8 KB

typedef float vfloat4 __attribute__((ext_vector_type(4)));

__global__ __launch_bounds__(256) void
pack_tables_kernel(const float* __restrict__ tables, unsigned* __restrict__ packed) {
    int g = blockIdx.x * blockDim.x + threadIdx.x;   // global bit index
    bool val = false;
    if (g < 65535) {
        int i = 31 - __clz(g + 1);            // row: (2^i - 1) <= g < (2^{i+1} - 1)
        int a = g - ((1 << i) - 1);           // address within row
        val = tables[i * 32768 + a] != 0.0f;
    }
    unsigned long long m = __ballot(val);
    if ((threadIdx.x & 63) == 0) {            // one writer per wave, 2 words
        packed[(g >> 5)]     = (unsigned)m;
        packed[(g >> 5) + 1] = (unsigned)(m >> 32);
    }
}

// int4 of {0,1} -> nibble (bit3 = first element in memory order)
__device__ __forceinline__ unsigned nib(const int4& m) {
    return (unsigned)((m.x << 3) | (m.y << 2) | (m.z << 1) | m.w);
}

// From packed per-lane nibbles, assemble my row value, do 16 bit-lookups,
// scatter results and store one float4 per lane per round.
__device__ __forceinline__ void
process_chunk(unsigned pk, const unsigned* __restrict__ tab,
              vfloat4* __restrict__ out4, size_t base, int lane) {
    // Gather: row L=lane needs quarter q from lane (L&15)*4+q, nibble L>>4.
    const int hi   = lane >> 4;
    const int bsrc = (lane & 15) << 2;
    unsigned v = 0;
    #pragma unroll
    for (int q = 0; q < 4; ++q) {
        unsigned x  = (unsigned)__shfl((int)pk, bsrc + q, 64);
        unsigned nb = (x >> (hi * 4)) & 0xFu;
        v |= nb << (12 - 4 * q);              // quarter q = value bits 15-4q..12-4q
    }

    // 16 independent LDS bit lookups; r16 bit i = output value bit i.
    unsigned r16 = 0;
    #pragma unroll
    for (int i = 0; i < 16; ++i) {
        unsigned mask = (1u << i) - 1u;
        unsigned bidx = mask + (v & mask);    // (2^i-1) + addr
        unsigned fl   = (tab[bidx >> 5] >> (bidx & 31u));
        r16 |= (((v >> i) ^ fl) & 1u) << i;
    }

    // Scatter + coalesced nontemporal stores: round j, lane t stores row
    // j*16+(t>>2), quarter t&3.
    #pragma unroll
    for (int j = 0; j < 4; ++j) {
        unsigned y = (unsigned)__shfl((int)r16, (j << 4) + (lane >> 2), 64);
        int q4 = (lane & 3) << 2;
        vfloat4 f;
        f.x = (float)((y >> (15 - q4)) & 1u);
        f.y = (float)((y >> (14 - q4)) & 1u);
        f.z = (float)((y >> (13 - q4)) & 1u);
        f.w = (float)((y >> (12 - q4)) & 1u);
        __builtin_nontemporal_store(f, &out4[base + j * 64 + lane]);
    }
}

__global__ __launch_bounds__(256) void
blm_kernel(const int4* __restrict__ bits4, const unsigned* __restrict__ packed,
           vfloat4* __restrict__ out4, int nrows) {
    __shared__ unsigned tab[PACK_WORDS];
    for (int k = threadIdx.x; k < PACK_WORDS; k += 256)
        tab[k] = packed[k];
    __syncthreads();

    const int lane    = threadIdx.x & 63;
    const int wave    = (blockIdx.x * 256 + threadIdx.x) >> 6;
    const int nwaves  = (gridDim.x * 256) >> 6;
    const int npairs  = nrows >> 7;           // 128 rows (2 chunks) per pair

    for (int p = wave; p < npairs; p += nwaves) {
        const size_t base = (size_t)p * 512;  // int4 index of pair start

        // Issue ALL 8 coalesced loads up front (8 KB/wave in flight).
        int4 a0 = bits4[base +   0 + lane];
        int4 a1 = bits4[base +  64 + lane];
        int4 a2 = bits4[base + 128 + lane];
        int4 a3 = bits4[base + 192 + lane];
        int4 b0 = bits4[base + 256 + lane];
        int4 b1 = bits4[base + 320 + lane];
        int4 b2 = bits4[base + 384 + lane];
        int4 b3 = bits4[base + 448 + lane];

        unsigned pkA = nib(a0) | (nib(a1) << 4) | (nib(a2) << 8) | (nib(a3) << 12);
        unsigned pkB = nib(b0) | (nib(b1) << 4) | (nib(b2) << 8) | (nib(b3) << 12);

        process_chunk(pkA, tab, out4, base,       lane);
        process_chunk(pkB, tab, out4, base + 256, lane);
    }
}

extern "C" void kernel_launch(void* const* d_in, const int* in_sizes, int n_in,
                              void* d_out, int out_size, void* d_ws, size_t ws_size,
                              hipStream_t stream) {
    const int*   bits   = (const int*)d_in[0];
    const float* tables = (const float*)d_in[1];
    float*       out    = (float*)d_out;
    unsigned*    packed = (unsigned*)d_ws;   // 8 KB used

    int nrows = in_sizes[0] / 16;            // 4194304

    pack_tables_kernel<<<65536 / 256, 256, 0, stream>>>(tables, packed);

    // 8192 blocks * 4 waves = 32768 waves; npairs = 32768 -> exactly 1 pair/wave
    blm_kernel<<<8192, 256, 0, stream>>>((const int4*)bits, packed,
                                         (vfloat4*)out, nrows);
}

// Round 5
// 449.828 us; speedup vs baseline: 1.0029x; 1.0029x over previous
//
#include <hip/hip_runtime.h>
#include <hip/hip_bf16.h>

// BitLevelMapper: bits [B,16] int32 {0,1} (mem index j holds value bit 15-j),
// tables [16, 32768] float32 {0,1}. For bit i: addr = value of bits 0..i-1,
// flip = tables[i][addr], out bit i = bit i ^ flip. Output float32, reversed
// layout like input.
//
// Live table = sum_i 2^i = 65535 bits ~= 8 KB packed -> LDS.
// R1: lane-contiguous global IO (16 B/lane), wave-shuffle row assembly.
// R2/R3: nontemporal output stores (write-once data).
// R4: persistent waves — 1024 blocks (4/CU co-resident), 16 chunks/wave with
//     depth-1 prefetch so the read stream stays continuously in flight
//     (R0-R3 all plateaued at ~165 us / 2.5 TB/s with one-shot waves).

#define PACK_WORDS 2048   // 65536 bits (65535 used), 8 KB

typedef float vfloat4 __attribute__((ext_vector_type(4)));

__global__ __launch_bounds__(256) void
pack_tables_kernel(const float* __restrict__ tables, unsigned* __restrict__ packed) {
    int g = blockIdx.x * blockDim.x + threadIdx.x;   // global bit index
    bool val = false;
    if (g < 65535) {
        int i = 31 - __clz(g + 1);            // row: (2^i - 1) <= g < (2^{i+1} - 1)
        int a = g - ((1 << i) - 1);           // address within row
        val = tables[i * 32768 + a] != 0.0f;
    }
    unsigned long long m = __ballot(val);
    if ((threadIdx.x & 63) == 0) {            // one writer per wave, 2 words
        packed[(g >> 5)]     = (unsigned)m;
        packed[(g >> 5) + 1] = (unsigned)(m >> 32);
    }
}

// int4 of {0,1} -> nibble (bit3 = first element in memory order)
__device__ __forceinline__ unsigned nib(const int4& m) {
    return (unsigned)((m.x << 3) | (m.y << 2) | (m.z << 1) | m.w);
}

// From per-lane packed nibbles (4 rounds x 4 bits), assemble my row value,
// 16 LDS bit-lookups, scatter results, one nt float4 store per lane per round.
__device__ __forceinline__ void
process_chunk(unsigned pk, const unsigned* __restrict__ tab,
              vfloat4* __restrict__ out4, size_t base, int lane) {
    // Gather: row L=lane needs quarter q from lane (L&15)*4+q, nibble L>>4.
    const int hi   = lane >> 4;
    const int bsrc = (lane & 15) << 2;
    unsigned v = 0;
    #pragma unroll
    for (int q = 0; q < 4; ++q) {
        unsigned x  = (unsigned)__shfl((int)pk, bsrc + q, 64);
        unsigned nb = (x >> (hi * 4)) & 0xFu;
        v |= nb << (12 - 4 * q);              // quarter q = value bits 15-4q..12-4q
    }

    // 16 independent LDS bit lookups; r16 bit i = output value bit i.
    unsigned r16 = 0;
    #pragma unroll
    for (int i = 0; i < 16; ++i) {
        unsigned mask = (1u << i) - 1u;
        unsigned bidx = mask + (v & mask);    // (2^i-1) + addr
        unsigned fl   = (tab[bidx >> 5] >> (bidx & 31u));
        r16 |= (((v >> i) ^ fl) & 1u) << i;
    }

    // Scatter + coalesced nontemporal stores: round j, lane t stores row
    // j*16+(t>>2), quarter t&3.
    #pragma unroll
    for (int j = 0; j < 4; ++j) {
        unsigned y = (unsigned)__shfl((int)r16, (j << 4) + (lane >> 2), 64);
        int q4 = (lane & 3) << 2;
        vfloat4 f;
        f.x = (float)((y >> (15 - q4)) & 1u);
        f.y = (float)((y >> (14 - q4)) & 1u);
        f.z = (float)((y >> (13 - q4)) & 1u);
        f.w = (float)((y >> (12 - q4)) & 1u);
        __builtin_nontemporal_store(f, &out4[base + j * 64 + lane]);
    }
}

__global__ __launch_bounds__(256) void
blm_kernel(const int4* __restrict__ bits4, const unsigned* __restrict__ packed,
           vfloat4* __restrict__ out4, int nrows) {
    __shared__ unsigned tab[PACK_WORDS];
    {   // stage 8 KB table once per block (int4-wide)
        const int4* p4 = (const int4*)packed;
        int4* t4 = (int4*)tab;
        for (int k = threadIdx.x; k < PACK_WORDS / 4; k += 256)
            t4[k] = p4[k];
    }
    __syncthreads();

    const int lane    = threadIdx.x & 63;
    const int wave    = (blockIdx.x * 256 + threadIdx.x) >> 6;
    const int nwaves  = (gridDim.x * 256) >> 6;
    const int nchunks = nrows >> 6;           // 64 rows / chunk

    int c = wave;
    if (c >= nchunks) return;

    // prologue: loads for first chunk
    size_t base = (size_t)c * 256;
    int4 m0 = bits4[base +   0 + lane];
    int4 m1 = bits4[base +  64 + lane];
    int4 m2 = bits4[base + 128 + lane];
    int4 m3 = bits4[base + 192 + lane];

    while (true) {
        int cn = c + nwaves;                  // uniform across wave
        int4 n0, n1, n2, n3;
        bool have_next = cn < nchunks;
        if (have_next) {                      // issue next chunk's loads FIRST
            size_t nb = (size_t)cn * 256;
            n0 = bits4[nb +   0 + lane];
            n1 = bits4[nb +  64 + lane];
            n2 = bits4[nb + 128 + lane];
            n3 = bits4[nb + 192 + lane];
        }

        unsigned pk = nib(m0) | (nib(m1) << 4) | (nib(m2) << 8) | (nib(m3) << 12);
        process_chunk(pk, tab, out4, base, lane);

        if (!have_next) break;
        m0 = n0; m1 = n1; m2 = n2; m3 = n3;
        c = cn; base = (size_t)c * 256;
    }
}

extern "C" void kernel_launch(void* const* d_in, const int* in_sizes, int n_in,
                              void* d_out, int out_size, void* d_ws, size_t ws_size,
                              hipStream_t stream) {
    const int*   bits   = (const int*)d_in[0];
    const float* tables = (const float*)d_in[1];
    float*       out    = (float*)d_out;
    unsigned*    packed = (unsigned*)d_ws;   // 8 KB used

    int nrows = in_sizes[0] / 16;            // 4194304

    pack_tables_kernel<<<65536 / 256, 256, 0, stream>>>(tables, packed);

    // 1024 blocks = 4/CU co-resident (LDS 8 KB, 4 waves each); 4096 waves,
    // nchunks = 65536 -> exactly 16 chunks per wave, steady-state streaming.
    blm_kernel<<<1024, 256, 0, stream>>>((const int4*)bits, packed,
                                         (vfloat4*)out, nrows);
}

// Round 6
// 428.865 us; speedup vs baseline: 1.0519x; 1.0489x over previous
//
#include <hip/hip_runtime.h>
#include <hip/hip_bf16.h>

// BitLevelMapper: bits [B,16] int32 {0,1} (mem index j holds value bit 15-j),
// tables [16, 32768] float32 {0,1}. For bit i: addr = value of bits 0..i-1,
// flip = tables[i][addr], out bit i = bit i ^ flip. Output float32, reversed
// layout like input.
//
// Live table = sum_i 2^i = 65535 bits ~= 8 KB packed -> LDS.
// R0-R4 history: strided, shuffle-coalesced, persistent+prefetch all plateau
// at ~163 us with every pipe idle (VALU 13%, HBM 40%, LDS ~0) — the fused
// read+transform+write structure itself is the suspect.
// R5: split into two unidirectional streaming passes through an 8 MB packed
// intermediate (L3-resident): compress (read-bound) + expand (write-bound).

#define PACK_WORDS 2048   // 65536 bits (65535 used), 8 KB

typedef float vfloat4 __attribute__((ext_vector_type(4)));

__global__ __launch_bounds__(256) void
pack_tables_kernel(const float* __restrict__ tables, unsigned* __restrict__ packed) {
    int g = blockIdx.x * blockDim.x + threadIdx.x;   // global bit index
    bool val = false;
    if (g < 65535) {
        int i = 31 - __clz(g + 1);            // row: (2^i - 1) <= g < (2^{i+1} - 1)
        int a = g - ((1 << i) - 1);           // address within row
        val = tables[i * 32768 + a] != 0.0f;
    }
    unsigned long long m = __ballot(val);
    if ((threadIdx.x & 63) == 0) {            // one writer per wave, 2 words
        packed[(g >> 5)]     = (unsigned)m;
        packed[(g >> 5) + 1] = (unsigned)(m >> 32);
    }
}

// Pass A: bits (int32 {0,1}) -> packed 16-bit row values (8 MB).
// Lane t loads quarter q=t&3 of row r=t>>2 (16 B, fully coalesced);
// quad OR-butterfly assembles v; one ushort store per quad.
__global__ __launch_bounds__(256) void
compress_kernel(const int4* __restrict__ bits4, unsigned short* __restrict__ rowv) {
    int t = blockIdx.x * 256 + threadIdx.x;
    int4 m = bits4[t];
    // nib bit3 = first element in memory order = value bit 15-4q
    unsigned nb = (unsigned)((m.x << 3) | (m.y << 2) | (m.z << 1) | m.w);
    unsigned part = nb << (12 - ((t & 3) << 2));
    part |= (unsigned)__shfl_xor((int)part, 1, 64);
    part |= (unsigned)__shfl_xor((int)part, 2, 64);
    if ((t & 3) == 0)
        rowv[t >> 2] = (unsigned short)part;  // rows consecutive per wave
}

// Pass B: packed row values + packed table -> float32 output (256 MB).
// Thread handles 4 quarter-rows (one float4 nt store each, coalesced).
__global__ __launch_bounds__(256) void
expand_kernel(const unsigned short* __restrict__ rowv,
              const unsigned* __restrict__ packed,
              vfloat4* __restrict__ out4) {
    __shared__ unsigned tab[PACK_WORDS];
    {   // stage 8 KB table (512 int4 / 256 threads = 2 each)
        const int4* p4 = (const int4*)packed;
        int4* t4 = (int4*)tab;
        t4[threadIdx.x]       = p4[threadIdx.x];
        t4[threadIdx.x + 256] = p4[threadIdx.x + 256];
    }
    __syncthreads();

    const size_t base = (size_t)blockIdx.x * 1024 + threadIdx.x;
    const int q4 = (int)(threadIdx.x & 3) << 2;      // 4*q, invariant across iters
    #pragma unroll
    for (int it = 0; it < 4; ++it) {
        size_t t = base + (size_t)it * 256;          // quarter index
        unsigned v = rowv[t >> 2];                   // 4 lanes share a row
        float o[4];
        #pragma unroll
        for (int j = 0; j < 4; ++j) {
            int i = 15 - q4 - j;                     // value bit for this slot
            unsigned mask = (1u << i) - 1u;
            unsigned bidx = mask + (v & mask);       // (2^i-1) + addr
            unsigned fl   = tab[bidx >> 5] >> (bidx & 31u);
            o[j] = (float)(((v >> i) ^ fl) & 1u);
        }
        vfloat4 f = {o[0], o[1], o[2], o[3]};
        __builtin_nontemporal_store(f, &out4[t]);
    }
}

extern "C" void kernel_launch(void* const* d_in, const int* in_sizes, int n_in,
                              void* d_out, int out_size, void* d_ws, size_t ws_size,
                              hipStream_t stream) {
    const int*      bits   = (const int*)d_in[0];
    const float*    tables = (const float*)d_in[1];
    float*          out    = (float*)d_out;
    unsigned*       packed = (unsigned*)d_ws;                     // 8 KB
    unsigned short* rowv   = (unsigned short*)((char*)d_ws + 8192); // 8 MB

    int nrows    = in_sizes[0] / 16;       // 4194304
    int nquarter = nrows * 4;              // 16777216

    pack_tables_kernel<<<65536 / 256, 256, 0, stream>>>(tables, packed);

    compress_kernel<<<nquarter / 256, 256, 0, stream>>>((const int4*)bits, rowv);

    // 4 quarters/thread -> 1024 quarters/block
    expand_kernel<<<nquarter / 1024, 256, 0, stream>>>(rowv, packed,
                                                       (vfloat4*)out);
}